// Round 7
// baseline (117.055 us; speedup 1.0000x reference)
//
#include <hip/hip_runtime.h>
#include <hip/hip_cooperative_groups.h>
#include <math.h>

namespace cg = cooperative_groups;

// Problem constants (from reference)
#define M_SLOTS 64
#define E_DIM   64
#define KEY_DIM 64
#define V_DIM   128
#define K_CAT   4
#define S_LEN   200

// ---------------- ws layout (float offsets) ----------------
#define OFF_C      0                          // 4096
#define OFF_BM     4096                       // 64
#define OFF_WBAR   4160                       // 64
#define OFF_BBAR   4224                       // 1
#define OFF_RM0    4288                       // 64
#define OFF_P0     4352                       // 64
#define OFF_WSUM   4416                       // S*M = 12800 (zeroed by k_pre)
#define OFF_EMSUM  (OFF_WSUM + S_LEN*M_SLOTS) // 200 (zeroed by k_pre, contiguous w/ wsum)
#define OFF_INV    17472                      // S*B f32 (fallback path only)
// fallback attn (bf16 exp, [S][16][B] uint2) at runtime offset OFF_INV + S*B

// work-item ranges for k_pre
#define PRE_C_END    4096
#define PRE_BM_END   4160
#define PRE_WBAR_END 4224
#define PRE_BBAR     4224
#define PRE_RM_BEG   4225
#define PRE_RM_END   4289
#define PRE_Z_BEG    4289
#define PRE_Z_END    (4289 + S_LEN*M_SLOTS + S_LEN)   // zero wsum+emsum

// pack two f32 -> bf16 pair (truncation) via v_perm
__device__ __forceinline__ unsigned pk2(float lo, float hi) {
    return __builtin_amdgcn_perm(__float_as_uint(hi), __float_as_uint(lo), 0x07060302u);
}

__device__ __forceinline__ void gpcm_store(float th, int q,
                                           const float* __restrict__ alpha_mean,
                                           const float* __restrict__ beta_base,
                                           const float* __restrict__ beta_gaps,
                                           float* __restrict__ out, size_t idx) {
    float a  = __expf(alpha_mean[q]);
    float b0 = beta_base[q];
    float2 g = *reinterpret_cast<const float2*>(&beta_gaps[q * (K_CAT - 2)]);
    float g0 = log1pf(__expf(g.x));
    float g1 = log1pf(__expf(g.y));
    float be1 = b0 + g0;
    float be2 = be1 + g1;
    float z0 = a * (th - b0);
    float z1 = a * (th - be1);
    float z2 = a * (th - be2);
    float c1 = z0, c2 = z0 + z1, c3 = z0 + z1 + z2;
    float cm = fmaxf(fmaxf(0.f, c1), fmaxf(c2, c3));
    float e0 = __expf(0.f - cm), e1 = __expf(c1 - cm), e2 = __expf(c2 - cm), e3 = __expf(c3 - cm);
    float si = __fdividef(1.0f, e0 + e1 + e2 + e3);
    float4 o4 = make_float4(e0 * si, e1 * si, e2 * si, e3 * si);
    *reinterpret_cast<float4*>(&out[idx * K_CAT]) = o4;
}

// Precompute C = q2k_w @ mkeys^T, bm, wbar, bbar, rm0, p0; zero wsum/emsum.
__global__ void k_pre(const float* __restrict__ q2k_w, const float* __restrict__ q2k_b,
                      const float* __restrict__ mkeys,
                      const float* __restrict__ ev_w, const float* __restrict__ ev_b,
                      const float* __restrict__ means, const float* __restrict__ logvars,
                      float* __restrict__ ws) {
    int gid = blockIdx.x * blockDim.x + threadIdx.x;
    if (gid < PRE_C_END) {
        int e = gid >> 6, m = gid & 63;
        float s = 0.f;
        #pragma unroll
        for (int k = 0; k < KEY_DIM; ++k) s = fmaf(q2k_w[e * KEY_DIM + k], mkeys[m * KEY_DIM + k], s);
        ws[OFF_C + gid] = s;
    } else if (gid < PRE_BM_END) {
        int m = gid - PRE_C_END;
        float s = 0.f;
        #pragma unroll
        for (int k = 0; k < KEY_DIM; ++k) s = fmaf(q2k_b[k], mkeys[m * KEY_DIM + k], s);
        ws[OFF_BM + m] = s;
    } else if (gid < PRE_WBAR_END) {
        int e = gid - PRE_BM_END;
        float s = 0.f;
        for (int v = 0; v < V_DIM; ++v) s += ev_w[e * V_DIM + v];
        ws[OFF_WBAR + e] = s * (1.0f / V_DIM);
    } else if (gid == PRE_BBAR) {
        float s = 0.f;
        for (int v = 0; v < V_DIM; ++v) s += ev_b[v];
        ws[OFF_BBAR] = s * (1.0f / V_DIM);
    } else if (gid >= PRE_RM_BEG && gid < PRE_RM_END) {
        int m = gid - PRE_RM_BEG;
        const float4* mr = (const float4*)(means + (size_t)m * V_DIM);
        float s = 0.f;
        #pragma unroll
        for (int i = 0; i < V_DIM / 4; ++i) { float4 v = mr[i]; s += (v.x + v.y) + (v.z + v.w); }
        ws[OFF_RM0 + m] = s * (1.0f / V_DIM);
        ws[OFF_P0 + m]  = __expf(-logvars[(size_t)m * V_DIM]);  // row-uniform by construction
    } else if (gid >= PRE_Z_BEG && gid < PRE_Z_END) {
        ws[OFF_WSUM + (gid - PRE_Z_BEG)] = 0.f;
    }
}

// ================= fused cooperative kernel =================
// Grid (S, B/256), 256 threads. Phase 1: per-thread 2 pair-halves matvec+exp,
// exps kept packed bf16 in regs; stats via fold + atomics. grid.sync().
// Phase 2: wave0 closed-form prefix rm_t. Phase 3: theta dot + GPCM.
__global__ __launch_bounds__(256, 3) void k_fused(
    const float* __restrict__ qtab, const int* __restrict__ qs, const int* __restrict__ rs,
    float* __restrict__ ws,
    const float* __restrict__ qa_w, const float* __restrict__ qa_b,
    const float* __restrict__ alpha_mean, const float* __restrict__ beta_base,
    const float* __restrict__ beta_gaps, float* __restrict__ out,
    int B, float invNQ, float invB)
{
    __shared__ float4 lsC[1040];
    __shared__ float4 lsEv[64];
    __shared__ float lsRm[M_SLOTS];
    const int tid = threadIdx.x, wv = tid >> 6, lane = tid & 63;
    const int half = lane >> 5, bl = lane & 31;
    const int t = blockIdx.x;

    float* wsum  = ws + OFF_WSUM;
    float* emsum = ws + OFF_EMSUM;

    const float4* C4 = (const float4*)(ws + OFF_C);
    #pragma unroll
    for (int i = 0; i < 4; ++i) lsC[tid + i * 256] = C4[tid + i * 256];
    if (tid < 16) lsC[1024 + tid] = ((const float4*)(ws + OFF_BM))[tid];
    if (tid < 64) lsEv[tid] = make_float4(qa_w[tid], qa_w[E_DIM + tid], qa_b[tid],
                                          ws[OFF_WBAR + tid]);
    const float bb = ws[OFF_BBAR];
    __syncthreads();

    uint2 pk[2][8];
    float inv[2];
    int   qv[2];
    float wfold = 0.f, evac = 0.f;

    #pragma unroll
    for (int it = 0; it < 2; ++it) {
        const int b = blockIdx.y * 256 + it * 128 + wv * 32 + bl;
        const int q = qs[(size_t)b * S_LEN + t];
        const int r = rs[(size_t)b * S_LEN + t];
        qv[it] = q;
        const float4* qr = (const float4*)(qtab + (size_t)q * E_DIM);
        float4 rq[16];
        #pragma unroll
        for (int i = 0; i < 16; ++i) rq[i] = qr[i];

        // logits for m = half*32 .. half*32+31
        float4 acc[8];
        #pragma unroll
        for (int j = 0; j < 8; ++j) acc[j] = lsC[1024 + half * 8 + j];
        #pragma unroll
        for (int e4 = 0; e4 < 16; ++e4) {
            #pragma unroll
            for (int s = 0; s < 4; ++s) {
                float qe = (s == 0) ? rq[e4].x : (s == 1) ? rq[e4].y : (s == 2) ? rq[e4].z : rq[e4].w;
                const int e = e4 * 4 + s;
                #pragma unroll
                for (int j = 0; j < 8; ++j) {
                    float4 cc = lsC[e * 16 + half * 8 + j];
                    acc[j].x = fmaf(qe, cc.x, acc[j].x);
                    acc[j].y = fmaf(qe, cc.y, acc[j].y);
                    acc[j].z = fmaf(qe, cc.z, acc[j].z);
                    acc[j].w = fmaf(qe, cc.w, acc[j].w);
                }
            }
        }
        // exp + cross-half sum
        float ssum = 0.f;
        #pragma unroll
        for (int j = 0; j < 8; ++j) {
            acc[j].x = __expf(acc[j].x); acc[j].y = __expf(acc[j].y);
            acc[j].z = __expf(acc[j].z); acc[j].w = __expf(acc[j].w);
            ssum += (acc[j].x + acc[j].y) + (acc[j].z + acc[j].w);
        }
        ssum += __shfl_xor(ssum, 32);
        inv[it] = __fdividef(1.0f, ssum);

        // keep unnormalized exp packed bf16 in regs
        #pragma unroll
        for (int j = 0; j < 8; ++j) {
            pk[it][j].x = pk2(acc[j].x, acc[j].y);
            pk[it][j].y = pk2(acc[j].z, acc[j].w);
        }

        // fold normalized attn over 32 pairs per half; lane (half*32+l) -> sum attn[m=lane]
        float av[32];
        #pragma unroll
        for (int j = 0; j < 8; ++j) {
            av[4 * j]     = acc[j].x * inv[it];
            av[4 * j + 1] = acc[j].y * inv[it];
            av[4 * j + 2] = acc[j].z * inv[it];
            av[4 * j + 3] = acc[j].w * inv[it];
        }
        #pragma unroll
        for (int step = 0; step < 5; ++step) {
            const int sh = 1 << step;
            #pragma unroll
            for (int j = 0; j < (32 >> step) / 2; ++j) {
                float p0 = av[2 * j]     + __shfl_xor(av[2 * j], sh);
                float p1 = av[2 * j + 1] + __shfl_xor(av[2 * j + 1], sh);
                av[j] = (lane & sh) ? p1 : p0;
            }
        }
        wfold += av[0];

        // evidence scalar: 32 e's per half, combine across halves
        float qn = (float)q * invNQ;
        float rn = (float)r * (1.0f / (K_CAT - 1));
        float evm = 0.f;
        #pragma unroll 8
        for (int e = 0; e < 32; ++e) {
            float4 p = lsEv[half * 32 + e];
            float qa = fmaf(qn, p.x, fmaf(rn, p.y, p.z));
            float ez = __expf(2.0f * qa);
            evm = fmaf(__fdividef(ez - 1.0f, ez + 1.0f), p.w, evm);
        }
        evm += __shfl_xor(evm, 32);   // full 64-e sum for this pair
        evac += evm + bb;
    }
    atomicAdd(&wsum[t * M_SLOTS + lane], wfold);
    {
        float es = evac;
        #pragma unroll
        for (int o = 16; o; o >>= 1) es += __shfl_xor(es, o);  // sum 64 pairs (per half)
        if (!lane) atomicAdd(&emsum[t], es);
    }

    cg::this_grid().sync();

    // Phase 2: wave 0 computes closed-form prefix rm_t for this t
    if (tid < 64) {
        float den = ws[OFF_P0 + tid];
        float num = den * ws[OFF_RM0 + tid];
        int s = 0;
        for (; s + 4 <= t; s += 4) {
            float w0 = wsum[(s + 0) * M_SLOTS + tid] * invB;
            float w1 = wsum[(s + 1) * M_SLOTS + tid] * invB;
            float w2 = wsum[(s + 2) * M_SLOTS + tid] * invB;
            float w3 = wsum[(s + 3) * M_SLOTS + tid] * invB;
            float e0 = emsum[s + 0], e1 = emsum[s + 1];
            float e2 = emsum[s + 2], e3 = emsum[s + 3];
            num = fmaf(e0 * invB, w0, num); den += w0;
            num = fmaf(e1 * invB, w1, num); den += w1;
            num = fmaf(e2 * invB, w2, num); den += w2;
            num = fmaf(e3 * invB, w3, num); den += w3;
        }
        for (; s < t; ++s) {
            float w = wsum[s * M_SLOTS + tid] * invB;
            num = fmaf(emsum[s] * invB, w, num);
            den += w;
        }
        lsRm[tid] = num / den;   // state BEFORE update at t
    }
    __syncthreads();

    // Phase 3: theta dot (own 32 m) + cross-half combine + GPCM
    const float4* rm4 = (const float4*)(lsRm + half * 32);
    #pragma unroll
    for (int it = 0; it < 2; ++it) {
        float th = 0.f;
        #pragma unroll
        for (int j = 0; j < 8; ++j) {
            float4 rm = rm4[j];
            th = fmaf(__uint_as_float(pk[it][j].x << 16),         rm.x, th);
            th = fmaf(__uint_as_float(pk[it][j].x & 0xffff0000u), rm.y, th);
            th = fmaf(__uint_as_float(pk[it][j].y << 16),         rm.z, th);
            th = fmaf(__uint_as_float(pk[it][j].y & 0xffff0000u), rm.w, th);
        }
        th = (th + __shfl_xor(th, 32)) * inv[it];
        if (!half) {
            const int b = blockIdx.y * 256 + it * 128 + wv * 32 + bl;
            gpcm_store(th, qv[it], alpha_mean, beta_base, beta_gaps, out, (size_t)b * S_LEN + t);
        }
    }
}

// ================= fallback path (round-6, proven) =================
__global__ __launch_bounds__(256, 3) void k_attn_ev(
    const float* __restrict__ qtab, const int* __restrict__ qs, const int* __restrict__ rs,
    const float* __restrict__ ws_ro,
    const float* __restrict__ qa_w, const float* __restrict__ qa_b,
    uint2* __restrict__ attnb, float* __restrict__ invb,
    float* __restrict__ wsum, float* __restrict__ emsum,
    int B, float invNQ)
{
    __shared__ float4 lsC[1040];
    __shared__ float4 lsEv[64];
    const int tid = threadIdx.x, wv = tid >> 6, lane = tid & 63;
    const int half = lane >> 5, bl = lane & 31;
    const int t = blockIdx.x;
    const int b = blockIdx.y * 128 + wv * 32 + bl;

    const int q = qs[(size_t)b * S_LEN + t];
    const int r = rs[(size_t)b * S_LEN + t];
    const float4* qr = (const float4*)(qtab + (size_t)q * E_DIM);
    float4 rq[16];
    #pragma unroll
    for (int i = 0; i < 16; ++i) rq[i] = qr[i];

    const float4* C4 = (const float4*)(ws_ro + OFF_C);
    #pragma unroll
    for (int i = 0; i < 4; ++i) lsC[tid + i * 256] = C4[tid + i * 256];
    if (tid < 16) lsC[1024 + tid] = ((const float4*)(ws_ro + OFF_BM))[tid];
    if (tid < 64) lsEv[tid] = make_float4(qa_w[tid], qa_w[E_DIM + tid], qa_b[tid],
                                          ws_ro[OFF_WBAR + tid]);
    const float bb = ws_ro[OFF_BBAR];
    __syncthreads();

    float4 acc[8];
    #pragma unroll
    for (int j = 0; j < 8; ++j) acc[j] = lsC[1024 + half * 8 + j];
    #pragma unroll
    for (int e4 = 0; e4 < 16; ++e4) {
        #pragma unroll
        for (int s = 0; s < 4; ++s) {
            float qe = (s == 0) ? rq[e4].x : (s == 1) ? rq[e4].y : (s == 2) ? rq[e4].z : rq[e4].w;
            const int e = e4 * 4 + s;
            #pragma unroll
            for (int j = 0; j < 8; ++j) {
                float4 cc = lsC[e * 16 + half * 8 + j];
                acc[j].x = fmaf(qe, cc.x, acc[j].x);
                acc[j].y = fmaf(qe, cc.y, acc[j].y);
                acc[j].z = fmaf(qe, cc.z, acc[j].z);
                acc[j].w = fmaf(qe, cc.w, acc[j].w);
            }
        }
    }
    float ssum = 0.f;
    #pragma unroll
    for (int j = 0; j < 8; ++j) {
        acc[j].x = __expf(acc[j].x); acc[j].y = __expf(acc[j].y);
        acc[j].z = __expf(acc[j].z); acc[j].w = __expf(acc[j].w);
        ssum += (acc[j].x + acc[j].y) + (acc[j].z + acc[j].w);
    }
    ssum += __shfl_xor(ssum, 32);
    float inv = __fdividef(1.0f, ssum);

    #pragma unroll
    for (int j = 0; j < 8; ++j) {
        uint2 pk;
        pk.x = pk2(acc[j].x, acc[j].y);
        pk.y = pk2(acc[j].z, acc[j].w);
        attnb[(size_t)(t * 16 + half * 8 + j) * B + b] = pk;
    }
    if (!half) invb[(size_t)t * B + b] = inv;

    float av[32];
    #pragma unroll
    for (int j = 0; j < 8; ++j) {
        av[4 * j]     = acc[j].x * inv;
        av[4 * j + 1] = acc[j].y * inv;
        av[4 * j + 2] = acc[j].z * inv;
        av[4 * j + 3] = acc[j].w * inv;
    }
    #pragma unroll
    for (int step = 0; step < 5; ++step) {
        const int sh = 1 << step;
        #pragma unroll
        for (int j = 0; j < (32 >> step) / 2; ++j) {
            float p0 = av[2 * j]     + __shfl_xor(av[2 * j], sh);
            float p1 = av[2 * j + 1] + __shfl_xor(av[2 * j + 1], sh);
            av[j] = (lane & sh) ? p1 : p0;
        }
    }
    atomicAdd(&wsum[t * M_SLOTS + lane], av[0]);

    float qn = (float)q * invNQ;
    float rn = (float)r * (1.0f / (K_CAT - 1));
    float evm = 0.f;
    #pragma unroll 8
    for (int e = 0; e < 32; ++e) {
        float4 p = lsEv[half * 32 + e];
        float qa = fmaf(qn, p.x, fmaf(rn, p.y, p.z));
        float ez = __expf(2.0f * qa);
        evm = fmaf(__fdividef(ez - 1.0f, ez + 1.0f), p.w, evm);
    }
    evm += __shfl_xor(evm, 32);
    evm += bb;
    #pragma unroll
    for (int o = 16; o; o >>= 1) evm += __shfl_xor(evm, o);
    if (!lane) atomicAdd(&emsum[t], evm);
}

__global__ __launch_bounds__(256) void k_out(
    const uint2* __restrict__ attnb, const float* __restrict__ invb,
    const float* __restrict__ ws_ro, const int* __restrict__ qs,
    const float* __restrict__ alpha_mean, const float* __restrict__ beta_base,
    const float* __restrict__ beta_gaps, float* __restrict__ out, int B, float invB)
{
    __shared__ float lsRm[M_SLOTS];
    const int tid = threadIdx.x;
    const int t = blockIdx.x;
    const int b = blockIdx.y * 256 + tid;
    const int q = qs[(size_t)b * S_LEN + t];

    uint2 v[16];
    #pragma unroll
    for (int mq = 0; mq < 16; ++mq) v[mq] = attnb[(size_t)(t * 16 + mq) * B + b];
    const float iv = invb[(size_t)t * B + b];

    if (tid < 64) {
        const float* wsum  = ws_ro + OFF_WSUM;
        const float* emsum = ws_ro + OFF_EMSUM;
        float den = ws_ro[OFF_P0 + tid];
        float num = den * ws_ro[OFF_RM0 + tid];
        int s = 0;
        for (; s + 4 <= t; s += 4) {
            float w0 = wsum[(s + 0) * M_SLOTS + tid] * invB;
            float w1 = wsum[(s + 1) * M_SLOTS + tid] * invB;
            float w2 = wsum[(s + 2) * M_SLOTS + tid] * invB;
            float w3 = wsum[(s + 3) * M_SLOTS + tid] * invB;
            float e0 = emsum[s + 0], e1 = emsum[s + 1];
            float e2 = emsum[s + 2], e3 = emsum[s + 3];
            num = fmaf(e0 * invB, w0, num); den += w0;
            num = fmaf(e1 * invB, w1, num); den += w1;
            num = fmaf(e2 * invB, w2, num); den += w2;
            num = fmaf(e3 * invB, w3, num); den += w3;
        }
        for (; s < t; ++s) {
            float w = wsum[s * M_SLOTS + tid] * invB;
            num = fmaf(emsum[s] * invB, w, num);
            den += w;
        }
        lsRm[tid] = num / den;
    }
    __syncthreads();

    const float4* rm4 = (const float4*)lsRm;
    float th = 0.f;
    #pragma unroll
    for (int mq = 0; mq < 16; ++mq) {
        float4 rm = rm4[mq];
        th = fmaf(__uint_as_float(v[mq].x << 16),         rm.x, th);
        th = fmaf(__uint_as_float(v[mq].x & 0xffff0000u), rm.y, th);
        th = fmaf(__uint_as_float(v[mq].y << 16),         rm.z, th);
        th = fmaf(__uint_as_float(v[mq].y & 0xffff0000u), rm.w, th);
    }
    th *= iv;
    gpcm_store(th, q, alpha_mean, beta_base, beta_gaps, out, (size_t)b * S_LEN + t);
}

extern "C" void kernel_launch(void* const* d_in, const int* in_sizes, int n_in,
                              void* d_out, int out_size, void* d_ws, size_t ws_size,
                              hipStream_t stream) {
    const float* qtab       = (const float*)d_in[0];
    const float* alpha_mean = (const float*)d_in[1];
    const float* beta_base  = (const float*)d_in[2];
    const float* beta_gaps  = (const float*)d_in[3];
    const float* ab_means   = (const float*)d_in[4];
    const float* ab_logvars = (const float*)d_in[5];
    const float* mkeys      = (const float*)d_in[6];
    const float* q2k_w      = (const float*)d_in[7];
    const float* q2k_b      = (const float*)d_in[8];
    const float* qa_w       = (const float*)d_in[9];
    const float* qa_b       = (const float*)d_in[10];
    const float* ev_w       = (const float*)d_in[11];
    const float* ev_b       = (const float*)d_in[12];
    const int*   qs         = (const int*)d_in[13];
    const int*   rs         = (const int*)d_in[14];
    float* out = (float*)d_out;
    float* ws  = (float*)d_ws;

    const int NQ = in_sizes[1];
    const int S  = S_LEN;
    int B = in_sizes[13] / S;   // 512

    k_pre<<<(PRE_Z_END + 255) / 256, 256, 0, stream>>>(
        q2k_w, q2k_b, mkeys, ev_w, ev_b, ab_means, ab_logvars, ws);

    float invNQ = 1.0f / (float)NQ;
    float invB  = 1.0f / (float)B;
    const float* qtab_a = qtab;
    const int* qs_a = qs; const int* rs_a = rs;
    float* ws_a = ws;
    const float* qaw_a = qa_w; const float* qab_a = qa_b;
    const float* am_a = alpha_mean; const float* bb_a = beta_base; const float* bg_a = beta_gaps;
    float* out_a = out;
    void* args[] = { (void*)&qtab_a, (void*)&qs_a, (void*)&rs_a, (void*)&ws_a,
                     (void*)&qaw_a, (void*)&qab_a, (void*)&am_a, (void*)&bb_a,
                     (void*)&bg_a, (void*)&out_a, (void*)&B, (void*)&invNQ, (void*)&invB };
    hipError_t err = hipLaunchCooperativeKernel(
        (const void*)k_fused, dim3(S, B / 256), dim3(256), args, 0, stream);

    if (err != hipSuccess) {
        // Fallback: proven round-6 two-kernel path.
        float* wsum  = ws + OFF_WSUM;
        float* emsum = ws + OFF_EMSUM;
        float* invb  = ws + OFF_INV;
        uint2* attnb = (uint2*)(ws + OFF_INV + (size_t)S * B);
        dim3 gA(S, B / 128);
        k_attn_ev<<<gA, 256, 0, stream>>>(qtab, qs, rs, ws, qa_w, qa_b,
                                          attnb, invb, wsum, emsum, B, invNQ);
        dim3 gO(S, B / 256);
        k_out<<<gO, 256, 0, stream>>>(attnb, invb, ws, qs, alpha_mean, beta_base,
                                      beta_gaps, out, B, invB);
    }
}

// Round 8
// 50.221 us; speedup vs baseline: 2.3308x; 2.3308x over previous
//
#include <hip/hip_runtime.h>
#include <math.h>

// Problem constants (from reference)
#define M_SLOTS 64
#define E_DIM   64
#define KEY_DIM 64
#define V_DIM   128
#define K_CAT   4
#define S_LEN   200

typedef __attribute__((ext_vector_type(8)))  short short8;
typedef __attribute__((ext_vector_type(16))) float f32x16;

// ---------------- ws layout (float offsets) ----------------
#define OFF_CT     0                          // 4096 ushort = 2048 f  (Ct[m][e] bf16)
#define OFF_BM     2048                       // 64
#define OFF_WBAR   2112                       // 64
#define OFF_BBAR   2176                       // 1
#define OFF_RM0    2240                       // 64
#define OFF_P0     2304                       // 64
#define OFF_WSUM   2368                       // S*M = 12800 (zeroed by k_pre)
#define OFF_EMSUM  (OFF_WSUM + S_LEN*M_SLOTS) // 200 (zeroed, contiguous w/ wsum)
#define OFF_INV    15424                      // S*B f32
#define OFF_ATTN   (OFF_INV + S_LEN*512)      // bf16 exp [S][16][B] as uint2 (13.1 MB)

// work-item ranges for k_pre
#define PRE_CT_END   4096
#define PRE_BM_END   4160
#define PRE_WBAR_END 4224
#define PRE_BBAR     4224
#define PRE_RM_BEG   4225
#define PRE_RM_END   4289
#define PRE_Z_BEG    4289
#define PRE_Z_END    (4289 + S_LEN*M_SLOTS + S_LEN)

// pack two f32 -> bf16 pair, truncation (for attnb storage)
__device__ __forceinline__ unsigned pk2(float lo, float hi) {
    return __builtin_amdgcn_perm(__float_as_uint(hi), __float_as_uint(lo), 0x07060302u);
}
// pack two f32 -> bf16 pair, round-to-nearest-even (for MFMA inputs)
__device__ __forceinline__ unsigned pk2rne(float lo, float hi) {
    unsigned ul = __float_as_uint(lo); ul += 0x7fffu + ((ul >> 16) & 1u);
    unsigned uh = __float_as_uint(hi); uh += 0x7fffu + ((uh >> 16) & 1u);
    return __builtin_amdgcn_perm(uh, ul, 0x07060302u);
}
__device__ __forceinline__ unsigned short bf16rne(float f) {
    unsigned u = __float_as_uint(f);
    return (unsigned short)((u + 0x7fffu + ((u >> 16) & 1u)) >> 16);
}
__device__ __forceinline__ short8 as_s8(uint4 u) { return __builtin_bit_cast(short8, u); }

__device__ __forceinline__ void gpcm_store(float th, int q,
                                           const float* __restrict__ alpha_mean,
                                           const float* __restrict__ beta_base,
                                           const float* __restrict__ beta_gaps,
                                           float* __restrict__ out, size_t idx) {
    float a  = __expf(alpha_mean[q]);
    float b0 = beta_base[q];
    float2 g = *reinterpret_cast<const float2*>(&beta_gaps[q * (K_CAT - 2)]);
    float g0 = log1pf(__expf(g.x));
    float g1 = log1pf(__expf(g.y));
    float be1 = b0 + g0;
    float be2 = be1 + g1;
    float z0 = a * (th - b0);
    float z1 = a * (th - be1);
    float z2 = a * (th - be2);
    float c1 = z0, c2 = z0 + z1, c3 = z0 + z1 + z2;
    float cm = fmaxf(fmaxf(0.f, c1), fmaxf(c2, c3));
    float e0 = __expf(0.f - cm), e1 = __expf(c1 - cm), e2 = __expf(c2 - cm), e3 = __expf(c3 - cm);
    float si = __fdividef(1.0f, e0 + e1 + e2 + e3);
    float4 o4 = make_float4(e0 * si, e1 * si, e2 * si, e3 * si);
    *reinterpret_cast<float4*>(&out[idx * K_CAT]) = o4;
}

// Precompute Ct[m][e] = (q2k_w @ mkeys^T)[e][m] in bf16, bm, wbar, bbar, rm0, p0; zero stats.
__global__ void k_pre(const float* __restrict__ q2k_w, const float* __restrict__ q2k_b,
                      const float* __restrict__ mkeys,
                      const float* __restrict__ ev_w, const float* __restrict__ ev_b,
                      const float* __restrict__ means, const float* __restrict__ logvars,
                      float* __restrict__ ws) {
    int gid = blockIdx.x * blockDim.x + threadIdx.x;
    if (gid < PRE_CT_END) {
        int e = gid >> 6, m = gid & 63;
        float s = 0.f;
        #pragma unroll
        for (int k = 0; k < KEY_DIM; ++k) s = fmaf(q2k_w[e * KEY_DIM + k], mkeys[m * KEY_DIM + k], s);
        ((unsigned short*)ws)[m * E_DIM + e] = bf16rne(s);   // transposed store
    } else if (gid < PRE_BM_END) {
        int m = gid - PRE_CT_END;
        float s = 0.f;
        #pragma unroll
        for (int k = 0; k < KEY_DIM; ++k) s = fmaf(q2k_b[k], mkeys[m * KEY_DIM + k], s);
        ws[OFF_BM + m] = s;
    } else if (gid < PRE_WBAR_END) {
        int e = gid - PRE_BM_END;
        float s = 0.f;
        for (int v = 0; v < V_DIM; ++v) s += ev_w[e * V_DIM + v];
        ws[OFF_WBAR + e] = s * (1.0f / V_DIM);
    } else if (gid == PRE_BBAR) {
        float s = 0.f;
        for (int v = 0; v < V_DIM; ++v) s += ev_b[v];
        ws[OFF_BBAR] = s * (1.0f / V_DIM);
    } else if (gid >= PRE_RM_BEG && gid < PRE_RM_END) {
        int m = gid - PRE_RM_BEG;
        const float4* mr = (const float4*)(means + (size_t)m * V_DIM);
        float s = 0.f;
        #pragma unroll
        for (int i = 0; i < V_DIM / 4; ++i) { float4 v = mr[i]; s += (v.x + v.y) + (v.z + v.w); }
        ws[OFF_RM0 + m] = s * (1.0f / V_DIM);
        ws[OFF_P0 + m]  = __expf(-logvars[(size_t)m * V_DIM]);  // row-uniform by construction
    } else if (gid >= PRE_Z_BEG && gid < PRE_Z_END) {
        ws[OFF_WSUM + (gid - PRE_Z_BEG)] = 0.f;
    }
}

// MFMA attention: wave computes 32 pairs x 64 slots via 8x v_mfma_f32_32x32x16_bf16.
// D layout: col(lane&31)=pair, row=(reg&3)+8*(reg>>2)+4*(lane>>5)+32*mtile = m.
// A = Ct[m][e] slices (global, L1-hot). B = gathered q-rows, bf16-packed in regs.
__global__ __launch_bounds__(256, 3) void k_attn(
    const float* __restrict__ qtab, const int* __restrict__ qs, const int* __restrict__ rs,
    const float* __restrict__ ws_ro,
    const float* __restrict__ qa_w, const float* __restrict__ qa_b,
    uint2* __restrict__ attnb, float* __restrict__ invb,
    float* __restrict__ wsum, float* __restrict__ emsum,
    int B, float invNQ)
{
    __shared__ float4 lsEv[64];
    const int tid = threadIdx.x, wv = tid >> 6, lane = tid & 63;
    const int h = lane >> 5, p = lane & 31;
    const int t = blockIdx.x;
    const int b = blockIdx.y * 128 + wv * 32 + p;

    const int q = qs[(size_t)b * S_LEN + t];
    const int r = rs[(size_t)b * S_LEN + t];

    // gather q-row halves for B-frags: slice s covers e = s*16 + h*8 .. +7
    const float* qrow = qtab + (size_t)q * E_DIM;
    float4 qf[8];
    #pragma unroll
    for (int s = 0; s < 4; ++s) {
        const float4* src = (const float4*)(qrow + s * 16 + h * 8);
        qf[2 * s]     = src[0];
        qf[2 * s + 1] = src[1];
    }

    // A-frags: lane reads Ct[m = p+32*mt][e = s*16 + h*8 ..+7] (16B)
    const unsigned short* ct = (const unsigned short*)ws_ro;
    uint4 af[8];
    #pragma unroll
    for (int mt = 0; mt < 2; ++mt)
        #pragma unroll
        for (int s = 0; s < 4; ++s)
            af[mt * 4 + s] = *(const uint4*)(ct + (p + 32 * mt) * E_DIM + s * 16 + h * 8);

    if (tid < 64) lsEv[tid] = make_float4(qa_w[tid], qa_w[E_DIM + tid], qa_b[tid],
                                          ws_ro[OFF_WBAR + tid]);
    const float bb = ws_ro[OFF_BBAR];

    // acc init with bm: reg group g (regs 4g..4g+3) -> m = 8g + 4h + 32*mt .. +3
    const float* bm = ws_ro + OFF_BM;
    f32x16 acc[2];
    #pragma unroll
    for (int mt = 0; mt < 2; ++mt)
        #pragma unroll
        for (int g = 0; g < 4; ++g) {
            float4 v = *(const float4*)(bm + 8 * g + 4 * h + 32 * mt);
            acc[mt][4 * g + 0] = v.x; acc[mt][4 * g + 1] = v.y;
            acc[mt][4 * g + 2] = v.z; acc[mt][4 * g + 3] = v.w;
        }

    // 4 K-slices x 2 m-tiles
    #pragma unroll
    for (int s = 0; s < 4; ++s) {
        uint4 bf;
        bf.x = pk2rne(qf[2 * s].x,     qf[2 * s].y);
        bf.y = pk2rne(qf[2 * s].z,     qf[2 * s].w);
        bf.z = pk2rne(qf[2 * s + 1].x, qf[2 * s + 1].y);
        bf.w = pk2rne(qf[2 * s + 1].z, qf[2 * s + 1].w);
        short8 bfr = as_s8(bf);
        acc[0] = __builtin_amdgcn_mfma_f32_32x32x16_bf16(as_s8(af[s]),     bfr, acc[0], 0, 0, 0);
        acc[1] = __builtin_amdgcn_mfma_f32_32x32x16_bf16(as_s8(af[4 + s]), bfr, acc[1], 0, 0, 0);
    }

    // softmax over the 64 slots of pair p (half h holds 32 of them)
    float av[32];
    float ssum = 0.f;
    #pragma unroll
    for (int j = 0; j < 16; ++j) { av[j]      = __expf(acc[0][j]); ssum += av[j]; }
    #pragma unroll
    for (int j = 0; j < 16; ++j) { av[16 + j] = __expf(acc[1][j]); ssum += av[16 + j]; }
    ssum += __shfl_xor(ssum, 32);
    const float inv = __fdividef(1.0f, ssum);

    // store unnormalized exp bf16 [t][slot=h*8+u][b]; slot word u covers j=4u..4u+3
    #pragma unroll
    for (int u = 0; u < 8; ++u) {
        uint2 pk;
        pk.x = pk2(av[4 * u],     av[4 * u + 1]);
        pk.y = pk2(av[4 * u + 2], av[4 * u + 3]);
        attnb[(size_t)(t * 16 + h * 8 + u) * B + b] = pk;
    }
    if (!h) invb[(size_t)t * B + b] = inv;

    // fold normalized attn over 32 pairs (within half); lane ends with index j=lane&31
    #pragma unroll
    for (int j = 0; j < 32; ++j) av[j] *= inv;
    #pragma unroll
    for (int step = 0; step < 5; ++step) {
        const int sh = 1 << step;
        #pragma unroll
        for (int j = 0; j < (32 >> step) / 2; ++j) {
            float p0 = av[2 * j]     + __shfl_xor(av[2 * j], sh);
            float p1 = av[2 * j + 1] + __shfl_xor(av[2 * j + 1], sh);
            av[j] = (lane & sh) ? p1 : p0;
        }
    }
    {
        const int jj = lane & 31;
        const int m = (jj & 3) + 8 * ((jj >> 2) & 3) + 4 * h + 32 * (jj >> 4);
        atomicAdd(&wsum[t * M_SLOTS + m], av[0]);
    }

    __syncthreads();   // lsEv ready

    // evidence scalar: halves cover 32 e each, combine, fold over 32 pairs
    float qn = (float)q * invNQ;
    float rn = (float)r * (1.0f / (K_CAT - 1));
    float evm = 0.f;
    #pragma unroll 8
    for (int e = 0; e < 32; ++e) {
        float4 pv = lsEv[h * 32 + e];
        float qa = fmaf(qn, pv.x, fmaf(rn, pv.y, pv.z));
        float ez = __expf(2.0f * qa);
        evm = fmaf(__fdividef(ez - 1.0f, ez + 1.0f), pv.w, evm);
    }
    evm += __shfl_xor(evm, 32);
    evm += bb;
    #pragma unroll
    for (int o = 16; o; o >>= 1) evm += __shfl_xor(evm, o);
    if (!lane) atomicAdd(&emsum[t], evm);
}

// k_out: wave0 computes closed-form prefix rm_t, writes PERMUTED to lsRmP (MFMA slot
// order); all threads theta-dot (bf16 exp from ws) + GPCM epilogue.
__global__ __launch_bounds__(256) void k_out(
    const uint2* __restrict__ attnb, const float* __restrict__ invb,
    const float* __restrict__ ws_ro, const int* __restrict__ qs,
    const float* __restrict__ alpha_mean, const float* __restrict__ beta_base,
    const float* __restrict__ beta_gaps, float* __restrict__ out, int B, float invB)
{
    __shared__ float lsRmP[M_SLOTS];
    const int tid = threadIdx.x;
    const int t = blockIdx.x;
    const int b = blockIdx.y * 256 + tid;
    const int q = qs[(size_t)b * S_LEN + t];

    uint2 v[16];
    #pragma unroll
    for (int s = 0; s < 16; ++s) v[s] = attnb[(size_t)(t * 16 + s) * B + b];
    const float iv = invb[(size_t)t * B + b];

    if (tid < 64) {   // wave 0: prefix for this t (m = tid)
        const float* wsum  = ws_ro + OFF_WSUM;
        const float* emsum = ws_ro + OFF_EMSUM;
        float den = ws_ro[OFF_P0 + tid];
        float num = den * ws_ro[OFF_RM0 + tid];
        int s = 0;
        for (; s + 4 <= t; s += 4) {
            float w0 = wsum[(s + 0) * M_SLOTS + tid] * invB;
            float w1 = wsum[(s + 1) * M_SLOTS + tid] * invB;
            float w2 = wsum[(s + 2) * M_SLOTS + tid] * invB;
            float w3 = wsum[(s + 3) * M_SLOTS + tid] * invB;
            float e0 = emsum[s + 0], e1 = emsum[s + 1];
            float e2 = emsum[s + 2], e3 = emsum[s + 3];
            num = fmaf(e0 * invB, w0, num); den += w0;
            num = fmaf(e1 * invB, w1, num); den += w1;
            num = fmaf(e2 * invB, w2, num); den += w2;
            num = fmaf(e3 * invB, w3, num); den += w3;
        }
        for (; s < t; ++s) {
            float w = wsum[s * M_SLOTS + tid] * invB;
            num = fmaf(emsum[s] * invB, w, num);
            den += w;
        }
        // permuted write: slot-vector index i for m=tid:
        // i = (m&3) + 4*((m>>3)&3) + 16*((m>>5)&1) + 32*((m>>2)&1)
        const int m = tid;
        const int i = (m & 3) + 4 * ((m >> 3) & 3) + 16 * ((m >> 5) & 1) + 32 * ((m >> 2) & 1);
        lsRmP[i] = num / den;
    }
    __syncthreads();

    const float4* rm4 = (const float4*)lsRmP;
    float th = 0.f;
    #pragma unroll
    for (int s = 0; s < 16; ++s) {
        float4 rm = rm4[s];
        th = fmaf(__uint_as_float(v[s].x << 16),         rm.x, th);
        th = fmaf(__uint_as_float(v[s].x & 0xffff0000u), rm.y, th);
        th = fmaf(__uint_as_float(v[s].y << 16),         rm.z, th);
        th = fmaf(__uint_as_float(v[s].y & 0xffff0000u), rm.w, th);
    }
    th *= iv;
    gpcm_store(th, q, alpha_mean, beta_base, beta_gaps, out, (size_t)b * S_LEN + t);
}

extern "C" void kernel_launch(void* const* d_in, const int* in_sizes, int n_in,
                              void* d_out, int out_size, void* d_ws, size_t ws_size,
                              hipStream_t stream) {
    const float* qtab       = (const float*)d_in[0];
    const float* alpha_mean = (const float*)d_in[1];
    const float* beta_base  = (const float*)d_in[2];
    const float* beta_gaps  = (const float*)d_in[3];
    const float* ab_means   = (const float*)d_in[4];
    const float* ab_logvars = (const float*)d_in[5];
    const float* mkeys      = (const float*)d_in[6];
    const float* q2k_w      = (const float*)d_in[7];
    const float* q2k_b      = (const float*)d_in[8];
    const float* qa_w       = (const float*)d_in[9];
    const float* qa_b       = (const float*)d_in[10];
    const float* ev_w       = (const float*)d_in[11];
    const float* ev_b       = (const float*)d_in[12];
    const int*   qs         = (const int*)d_in[13];
    const int*   rs         = (const int*)d_in[14];
    float* out = (float*)d_out;
    float* ws  = (float*)d_ws;

    const int NQ = in_sizes[1];
    const int S  = S_LEN;
    const int B  = in_sizes[13] / S;   // 512

    float* wsum  = ws + OFF_WSUM;
    float* emsum = ws + OFF_EMSUM;
    float* invb  = ws + OFF_INV;
    uint2* attnb = (uint2*)(ws + OFF_ATTN);

    k_pre<<<(PRE_Z_END + 255) / 256, 256, 0, stream>>>(
        q2k_w, q2k_b, mkeys, ev_w, ev_b, ab_means, ab_logvars, ws);

    dim3 gA(S, B / 128);
    k_attn<<<gA, 256, 0, stream>>>(qtab, qs, rs, ws, qa_w, qa_b,
                                   attnb, invb, wsum, emsum, B, 1.0f / (float)NQ);

    dim3 gO(S, B / 256);
    k_out<<<gO, 256, 0, stream>>>(attnb, invb, ws, qs, alpha_mean, beta_base,
                                  beta_gaps, out, B, 1.0f / (float)B);
}

// Round 9
// 49.367 us; speedup vs baseline: 2.3711x; 1.0173x over previous
//
#include <hip/hip_runtime.h>
#include <math.h>

// Problem constants (from reference)
#define M_SLOTS 64
#define E_DIM   64
#define KEY_DIM 64
#define V_DIM   128
#define K_CAT   4
#define S_LEN   200

typedef __attribute__((ext_vector_type(8)))  short short8;
typedef __attribute__((ext_vector_type(16))) float f32x16;

// ---------------- ws layout (float offsets) ----------------
#define OFF_CT     0                          // 4096 ushort = 2048 f  (Ct[m][e] bf16)
#define OFF_BM     2048                       // 64
#define OFF_WBAR   2112                       // 64
#define OFF_BBAR   2176                       // 1
#define OFF_RM0    2240                       // 64
#define OFF_P0     2304                       // 64
#define OFF_WSUM   2368                       // S*M = 12800 (zeroed by k_pre)
#define OFF_EMSUM  (OFF_WSUM + S_LEN*M_SLOTS) // 200 (zeroed, contiguous w/ wsum)

// work-item ranges for k_pre
#define PRE_CT_END   4096
#define PRE_BM_END   4160
#define PRE_WBAR_END 4224
#define PRE_BBAR     4224
#define PRE_RM_BEG   4225
#define PRE_RM_END   4289
#define PRE_Z_BEG    4289
#define PRE_Z_END    (4289 + S_LEN*M_SLOTS + S_LEN)

// pack two f32 -> bf16 pair, round-to-nearest-even (for MFMA inputs)
__device__ __forceinline__ unsigned pk2rne(float lo, float hi) {
    unsigned ul = __float_as_uint(lo); ul += 0x7fffu + ((ul >> 16) & 1u);
    unsigned uh = __float_as_uint(hi); uh += 0x7fffu + ((uh >> 16) & 1u);
    return __builtin_amdgcn_perm(uh, ul, 0x07060302u);
}
__device__ __forceinline__ unsigned short bf16rne(float f) {
    unsigned u = __float_as_uint(f);
    return (unsigned short)((u + 0x7fffu + ((u >> 16) & 1u)) >> 16);
}
__device__ __forceinline__ short8 as_s8(uint4 u) { return __builtin_bit_cast(short8, u); }

__device__ __forceinline__ void gpcm_store(float th, int q,
                                           const float* __restrict__ alpha_mean,
                                           const float* __restrict__ beta_base,
                                           const float* __restrict__ beta_gaps,
                                           float* __restrict__ out, size_t idx) {
    float a  = __expf(alpha_mean[q]);
    float b0 = beta_base[q];
    float2 g = *reinterpret_cast<const float2*>(&beta_gaps[q * (K_CAT - 2)]);
    float g0 = log1pf(__expf(g.x));
    float g1 = log1pf(__expf(g.y));
    float be1 = b0 + g0;
    float be2 = be1 + g1;
    float z0 = a * (th - b0);
    float z1 = a * (th - be1);
    float z2 = a * (th - be2);
    float c1 = z0, c2 = z0 + z1, c3 = z0 + z1 + z2;
    float cm = fmaxf(fmaxf(0.f, c1), fmaxf(c2, c3));
    float e0 = __expf(0.f - cm), e1 = __expf(c1 - cm), e2 = __expf(c2 - cm), e3 = __expf(c3 - cm);
    float si = __fdividef(1.0f, e0 + e1 + e2 + e3);
    float4 o4 = make_float4(e0 * si, e1 * si, e2 * si, e3 * si);
    *reinterpret_cast<float4*>(&out[idx * K_CAT]) = o4;
}

// Shared MFMA matvec: lane covers pair p (col), half h (k-slices + m rows 4h..).
// acc[mt][j] = logit for m = (j&3) + 8*((j>>2)&3) + 4*h + 32*mt, pair = p.
__device__ __forceinline__ void mfma_logits(
    const float* __restrict__ qrow, const unsigned short* __restrict__ ct,
    const float* __restrict__ bm, int h, int p, f32x16 acc[2])
{
    float4 qf[8];
    #pragma unroll
    for (int s = 0; s < 4; ++s) {
        const float4* src = (const float4*)(qrow + s * 16 + h * 8);
        qf[2 * s]     = src[0];
        qf[2 * s + 1] = src[1];
    }
    uint4 af[8];
    #pragma unroll
    for (int mt = 0; mt < 2; ++mt)
        #pragma unroll
        for (int s = 0; s < 4; ++s)
            af[mt * 4 + s] = *(const uint4*)(ct + (p + 32 * mt) * E_DIM + s * 16 + h * 8);
    #pragma unroll
    for (int mt = 0; mt < 2; ++mt)
        #pragma unroll
        for (int g = 0; g < 4; ++g) {
            float4 v = *(const float4*)(bm + 8 * g + 4 * h + 32 * mt);
            acc[mt][4 * g + 0] = v.x; acc[mt][4 * g + 1] = v.y;
            acc[mt][4 * g + 2] = v.z; acc[mt][4 * g + 3] = v.w;
        }
    #pragma unroll
    for (int s = 0; s < 4; ++s) {
        uint4 bf;
        bf.x = pk2rne(qf[2 * s].x,     qf[2 * s].y);
        bf.y = pk2rne(qf[2 * s].z,     qf[2 * s].w);
        bf.z = pk2rne(qf[2 * s + 1].x, qf[2 * s + 1].y);
        bf.w = pk2rne(qf[2 * s + 1].z, qf[2 * s + 1].w);
        short8 bfr = as_s8(bf);
        acc[0] = __builtin_amdgcn_mfma_f32_32x32x16_bf16(as_s8(af[s]),     bfr, acc[0], 0, 0, 0);
        acc[1] = __builtin_amdgcn_mfma_f32_32x32x16_bf16(as_s8(af[4 + s]), bfr, acc[1], 0, 0, 0);
    }
}

// Precompute Ct[m][e] bf16, bm, wbar, bbar, rm0, p0; zero wsum/emsum.
__global__ void k_pre(const float* __restrict__ q2k_w, const float* __restrict__ q2k_b,
                      const float* __restrict__ mkeys,
                      const float* __restrict__ ev_w, const float* __restrict__ ev_b,
                      const float* __restrict__ means, const float* __restrict__ logvars,
                      float* __restrict__ ws) {
    int gid = blockIdx.x * blockDim.x + threadIdx.x;
    if (gid < PRE_CT_END) {
        int e = gid >> 6, m = gid & 63;
        float s = 0.f;
        #pragma unroll
        for (int k = 0; k < KEY_DIM; ++k) s = fmaf(q2k_w[e * KEY_DIM + k], mkeys[m * KEY_DIM + k], s);
        ((unsigned short*)ws)[m * E_DIM + e] = bf16rne(s);   // transposed store
    } else if (gid < PRE_BM_END) {
        int m = gid - PRE_CT_END;
        float s = 0.f;
        #pragma unroll
        for (int k = 0; k < KEY_DIM; ++k) s = fmaf(q2k_b[k], mkeys[m * KEY_DIM + k], s);
        ws[OFF_BM + m] = s;
    } else if (gid < PRE_WBAR_END) {
        int e = gid - PRE_BM_END;
        float s = 0.f;
        for (int v = 0; v < V_DIM; ++v) s += ev_w[e * V_DIM + v];
        ws[OFF_WBAR + e] = s * (1.0f / V_DIM);
    } else if (gid == PRE_BBAR) {
        float s = 0.f;
        for (int v = 0; v < V_DIM; ++v) s += ev_b[v];
        ws[OFF_BBAR] = s * (1.0f / V_DIM);
    } else if (gid >= PRE_RM_BEG && gid < PRE_RM_END) {
        int m = gid - PRE_RM_BEG;
        const float4* mr = (const float4*)(means + (size_t)m * V_DIM);
        float s = 0.f;
        #pragma unroll
        for (int i = 0; i < V_DIM / 4; ++i) { float4 v = mr[i]; s += (v.x + v.y) + (v.z + v.w); }
        ws[OFF_RM0 + m] = s * (1.0f / V_DIM);
        ws[OFF_P0 + m]  = __expf(-logvars[(size_t)m * V_DIM]);  // row-uniform by construction
    } else if (gid >= PRE_Z_BEG && gid < PRE_Z_END) {
        ws[OFF_WSUM + (gid - PRE_Z_BEG)] = 0.f;
    }
}

// Stats-only attention: MFMA logits -> softmax -> fold -> atomics. No attn store.
__global__ __launch_bounds__(256, 3) void k_attn(
    const float* __restrict__ qtab, const int* __restrict__ qs, const int* __restrict__ rs,
    const float* __restrict__ ws_ro,
    const float* __restrict__ qa_w, const float* __restrict__ qa_b,
    float* __restrict__ wsum, float* __restrict__ emsum,
    int B, float invNQ)
{
    __shared__ float4 lsEv[64];
    const int tid = threadIdx.x, wv = tid >> 6, lane = tid & 63;
    const int h = lane >> 5, p = lane & 31;
    const int t = blockIdx.x;
    const int b = blockIdx.y * 128 + wv * 32 + p;

    const int q = qs[(size_t)b * S_LEN + t];
    const int r = rs[(size_t)b * S_LEN + t];

    if (tid < 64) lsEv[tid] = make_float4(qa_w[tid], qa_w[E_DIM + tid], qa_b[tid],
                                          ws_ro[OFF_WBAR + tid]);
    const float bb = ws_ro[OFF_BBAR];

    f32x16 acc[2];
    mfma_logits(qtab + (size_t)q * E_DIM, (const unsigned short*)ws_ro,
                ws_ro + OFF_BM, h, p, acc);

    // softmax over 64 slots of pair p (half h holds 32)
    float av[32];
    float ssum = 0.f;
    #pragma unroll
    for (int j = 0; j < 16; ++j) { av[j]      = __expf(acc[0][j]); ssum += av[j]; }
    #pragma unroll
    for (int j = 0; j < 16; ++j) { av[16 + j] = __expf(acc[1][j]); ssum += av[16 + j]; }
    ssum += __shfl_xor(ssum, 32);
    const float inv = __fdividef(1.0f, ssum);

    // fold normalized attn over 32 pairs (within half); lane ends with j=lane&31
    #pragma unroll
    for (int j = 0; j < 32; ++j) av[j] *= inv;
    #pragma unroll
    for (int step = 0; step < 5; ++step) {
        const int sh = 1 << step;
        #pragma unroll
        for (int j = 0; j < (32 >> step) / 2; ++j) {
            float p0 = av[2 * j]     + __shfl_xor(av[2 * j], sh);
            float p1 = av[2 * j + 1] + __shfl_xor(av[2 * j + 1], sh);
            av[j] = (lane & sh) ? p1 : p0;
        }
    }
    {
        const int jj = lane & 31;
        const int m = (jj & 3) + 8 * ((jj >> 2) & 3) + 4 * h + 32 * (jj >> 4);
        atomicAdd(&wsum[t * M_SLOTS + m], av[0]);
    }

    __syncthreads();   // lsEv ready

    // evidence scalar
    float qn = (float)q * invNQ;
    float rn = (float)r * (1.0f / (K_CAT - 1));
    float evm = 0.f;
    #pragma unroll 8
    for (int e = 0; e < 32; ++e) {
        float4 pv = lsEv[h * 32 + e];
        float qa = fmaf(qn, pv.x, fmaf(rn, pv.y, pv.z));
        float ez = __expf(2.0f * qa);
        evm = fmaf(__fdividef(ez - 1.0f, ez + 1.0f), pv.w, evm);
    }
    evm += __shfl_xor(evm, 32);
    evm += bb;
    #pragma unroll
    for (int o = 16; o; o >>= 1) evm += __shfl_xor(evm, o);
    if (!lane) atomicAdd(&emsum[t], evm);
}

// Output: 4-wave-parallel associative prefix for rm_t, then MFMA recompute of
// logits, softmax, theta dot, GPCM. No attn buffer traffic.
__global__ __launch_bounds__(256, 3) void k_out(
    const float* __restrict__ qtab, const int* __restrict__ qs,
    const float* __restrict__ ws_ro,
    const float* __restrict__ alpha_mean, const float* __restrict__ beta_base,
    const float* __restrict__ beta_gaps, float* __restrict__ out, int B, float invB)
{
    __shared__ float lsW[4][M_SLOTS], lsN[4][M_SLOTS];
    __shared__ float lsRmP[M_SLOTS];
    const int tid = threadIdx.x, wv = tid >> 6, lane = tid & 63;
    const int h = lane >> 5, p = lane & 31;
    const int t = blockIdx.x;
    const int b = blockIdx.y * 128 + wv * 32 + p;

    const int q = qs[(size_t)b * S_LEN + t];

    // ---- prefix partials: wave wv sums segment [s0,s1) over m=lane (associative) ----
    {
        const float* wsum  = ws_ro + OFF_WSUM;
        const float* emsum = ws_ro + OFF_EMSUM;
        const int seg = (t + 3) >> 2;
        const int s0 = wv * seg, s1 = min(s0 + seg, t);
        float pw = 0.f, pn = 0.f;
        for (int s = s0; s < s1; ++s) {
            float w = wsum[s * M_SLOTS + lane];
            pw += w;
            pn = fmaf(emsum[s], w, pn);
        }
        lsW[wv][lane] = pw; lsN[wv][lane] = pn;
    }
    __syncthreads();
    if (tid < 64) {
        const int m = tid;
        float sw = lsW[0][m] + lsW[1][m] + lsW[2][m] + lsW[3][m];
        float sn = lsN[0][m] + lsN[1][m] + lsN[2][m] + lsN[3][m];
        float den = ws_ro[OFF_P0 + m] + sw * invB;
        float num = ws_ro[OFF_P0 + m] * ws_ro[OFF_RM0 + m] + sn * (invB * invB);
        // slot-permuted index: idx = h(m)*32 + mt(m)*16 + j(m)
        const int idx = ((m >> 2) & 1) * 32 + ((m >> 5) & 1) * 16 + (m & 3) + 4 * ((m >> 3) & 3);
        lsRmP[idx] = num / den;
    }
    __syncthreads();

    // ---- MFMA recompute ----
    f32x16 acc[2];
    mfma_logits(qtab + (size_t)q * E_DIM, (const unsigned short*)ws_ro,
                ws_ro + OFF_BM, h, p, acc);

    float ssum = 0.f, th = 0.f;
    const float* rmh = lsRmP + h * 32;
    #pragma unroll
    for (int j = 0; j < 16; ++j) {
        float e = __expf(acc[0][j]);
        ssum += e;
        th = fmaf(e, rmh[j], th);
    }
    #pragma unroll
    for (int j = 0; j < 16; ++j) {
        float e = __expf(acc[1][j]);
        ssum += e;
        th = fmaf(e, rmh[16 + j], th);
    }
    ssum += __shfl_xor(ssum, 32);
    th   += __shfl_xor(th, 32);
    th = __fdividef(th, ssum);

    if (!h) gpcm_store(th, q, alpha_mean, beta_base, beta_gaps, out, (size_t)b * S_LEN + t);
}

extern "C" void kernel_launch(void* const* d_in, const int* in_sizes, int n_in,
                              void* d_out, int out_size, void* d_ws, size_t ws_size,
                              hipStream_t stream) {
    const float* qtab       = (const float*)d_in[0];
    const float* alpha_mean = (const float*)d_in[1];
    const float* beta_base  = (const float*)d_in[2];
    const float* beta_gaps  = (const float*)d_in[3];
    const float* ab_means   = (const float*)d_in[4];
    const float* ab_logvars = (const float*)d_in[5];
    const float* mkeys      = (const float*)d_in[6];
    const float* q2k_w      = (const float*)d_in[7];
    const float* q2k_b      = (const float*)d_in[8];
    const float* qa_w       = (const float*)d_in[9];
    const float* qa_b       = (const float*)d_in[10];
    const float* ev_w       = (const float*)d_in[11];
    const float* ev_b       = (const float*)d_in[12];
    const int*   qs         = (const int*)d_in[13];
    const int*   rs         = (const int*)d_in[14];
    float* out = (float*)d_out;
    float* ws  = (float*)d_ws;

    const int NQ = in_sizes[1];
    const int S  = S_LEN;
    const int B  = in_sizes[13] / S;   // 512

    float* wsum  = ws + OFF_WSUM;
    float* emsum = ws + OFF_EMSUM;

    k_pre<<<(PRE_Z_END + 255) / 256, 256, 0, stream>>>(
        q2k_w, q2k_b, mkeys, ev_w, ev_b, ab_means, ab_logvars, ws);

    dim3 g(S, B / 128);
    k_attn<<<g, 256, 0, stream>>>(qtab, qs, rs, ws, qa_w, qa_b,
                                  wsum, emsum, B, 1.0f / (float)NQ);

    k_out<<<g, 256, 0, stream>>>(qtab, qs, ws, alpha_mean, beta_base,
                                 beta_gaps, out, B, 1.0f / (float)B);
}